// Round 13
// baseline (1496.489 us; speedup 1.0000x reference)
//
#include <hip/hip_runtime.h>

#define NPTS 8192
#define NCH 8
#define STRIDE 6144
#define TOTAL 51200
#define FADE 1228
#define SEG 32
#define SEGLEN 256   // NPTS / SEG
#define JB 2         // j's per thread in argmin
#define TEAMS 4      // t-range teams per argmin block
#define TLEN 64      // SEGLEN / TEAMS
#define SROWS 16     // smoother rows per block (512 blocks = 2/CU)
#define NCOL 16      // argmin grid.x (columns of 512 j's)

typedef unsigned long long u64;

// ---------------------------------------------------------------------------
// copy ALL chunks -> fin, init jmax to -1, init packed argmin buffers,
// pre-transpose bs_w2 into W2T, zero the per-column resolve tickets.
__global__ void k_setup(const float* __restrict__ chunks, float* __restrict__ fin,
                        int* __restrict__ jmax_all, unsigned int* __restrict__ packed32,
                        const float* __restrict__ w2g, float* __restrict__ W2T,
                        int* __restrict__ tickets) {
    int i = blockIdx.x * 256 + threadIdx.x;            // grid covers 196608
    if (i < NCH * NPTS * 3) fin[i] = chunks[i];
    if (i < (NCH - 1) * NPTS) jmax_all[i] = -1;
    if (i < (NCH - 1) * NPTS * 2) packed32[i] = 0xFFFFFFFFu;
    if (i < 5120) {
        int co = i / 160;
        int r = i - co * 160;
        int ci = r / 5;
        int k = r - ci * 5;
        W2T[(ci * 5 + k) * 32 + co] = w2g[i];
    }
    if (i < (NCH - 1) * NCOL) tickets[i] = 0;
}

// ---------------------------------------------------------------------------
// Argmin (verbatim round-12 body) + LAST-BLOCK-IN-COLUMN RESOLVE.
// Grid (16, 32): column x owns j in [x*512, x*512+512); 32 y-blocks reduce
// packed[j] via lexicographic (d,k) atomicMin. After its atomicMins, each
// block fences + tickets; the 32nd block per column becomes the tail and
// runs the resolve for the column's 512 j's (overlapping other columns'
// argmin). packed[] is read with atomicAdd(p,0) -- device-scope atomic
// reads, immune to cross-XCD L2 staleness (Guideline 16). Resolve body =
// round-9/10 verified wave-parallel shuffle-MLP (bit-exact twice): wave w
// owns 32 j's; chains verbatim; registers tiny so launch_bounds(1024,8)
// (2 blocks/CU argmin occupancy) is preserved -- avoids the round-3
// thread-per-j spill pathology. Saves 7 launches (23 -> 16).
__global__ __launch_bounds__(1024, 8) void k_argmin(const float* __restrict__ P,
        const float* __restrict__ C, u64* __restrict__ packed,
        int* __restrict__ ticket,
        const float* __restrict__ wp_w1, const float* __restrict__ wp_b1,
        const float* __restrict__ wp_w2, const float* __restrict__ wp_b2,
        const float* __restrict__ wp_w3, const float* __restrict__ wp_b3,
        float* __restrict__ fused, int* __restrict__ mi, int* __restrict__ jmax) {
#pragma clang fp contract(off)
    __shared__ float4 sh[SEGLEN];
    __shared__ u64 pkbuf[TEAMS - 1][256 * JB];
    __shared__ float Wp[780];   // w1[0:192) b1[192:224) w2[224:736) b2[736:752) w3[752:768) b3[768]
    __shared__ float Wt2[512];  // wp_w2 transposed: [ci*16+o]
    __shared__ int lastFlag;
    int tid = threadIdx.x;
    int lt   = tid & 255;          // lane within team (0..255)
    int team = tid >> 8;           // 0..3
    int k0 = blockIdx.y * SEGLEN;
    if (tid < SEGLEN) {
        int k = k0 + tid;
        float x = C[k * 3 + 0], y = C[k * 3 + 1], z = C[k * 3 + 2];
        float cc = (x * x + y * y) + z * z;
        sh[tid] = make_float4(x, y, z, cc);
    }
    __syncthreads();
    int j0 = blockIdx.x * (256 * JB) + lt * JB;
    const float2* Pv = (const float2*)(P + j0 * 3);    // 6 floats, 8B-aligned (j0 even)
    float2 a = Pv[0], b = Pv[1], c2 = Pv[2];
    float p0[JB] = {a.x, b.y};
    float p1[JB] = {a.y, c2.x};
    float p2[JB] = {b.x, c2.y};
    float pp[JB], best[JB];
    int bt[JB];
    int t0 = team * TLEN;
#pragma unroll
    for (int i = 0; i < JB; ++i) {
        pp[i] = (p0[i] * p0[i] + p1[i] * p1[i]) + p2[i] * p2[i];
        best[i] = 3.4e38f;
        bt[i] = t0;
    }
#pragma unroll 4
    for (int tt = 0; tt < TLEN; ++tt) {
        int t = t0 + tt;
        float4 f = sh[t];
#pragma unroll
        for (int i = 0; i < JB; ++i) {
            float g = __builtin_fmaf(p2[i], f.z, __builtin_fmaf(p1[i], f.y, p0[i] * f.x));
            float sadd = pp[i] + f.w;
            float d = __builtin_fmaf(-2.0f, g, sadd);
            if (d < best[i]) { best[i] = d; bt[i] = t; }   // strict <: lowest t wins ties
        }
    }
    u64 pk[JB];
#pragma unroll
    for (int i = 0; i < JB; ++i) {
        unsigned ud = __float_as_uint(best[i]);
        if (ud == 0x80000000u) ud = 0u;                 // canonicalize -0 -> +0 (bitwise)
        ud = (ud & 0x80000000u) ? ~ud : (ud | 0x80000000u);   // order-preserving map
        pk[i] = ((u64)ud << 32) | (u64)(unsigned)(k0 + bt[i]);
    }
    if (team > 0) {
#pragma unroll
        for (int i = 0; i < JB; ++i) pkbuf[team - 1][lt * JB + i] = pk[i];
    }
    __syncthreads();
    if (team == 0) {
#pragma unroll
        for (int i = 0; i < JB; ++i) {
            u64 v = pk[i];
            u64 v1 = pkbuf[0][lt * JB + i];
            u64 v2 = pkbuf[1][lt * JB + i];
            u64 v3 = pkbuf[2][lt * JB + i];
            if (v1 < v) v = v1;
            if (v2 < v) v = v2;
            if (v3 < v) v = v3;
            atomicMin(&packed[j0 + i], v);
        }
    }
    __syncthreads();               // all atomicMins of this block drained (vmcnt at barrier)

    // ---- ticket: last block per column proceeds to resolve ----
    if (tid == 0) {
        __threadfence();           // release: our atomicMins visible device-wide
        int t = atomicAdd(&ticket[blockIdx.x], 1);
        lastFlag = (t == SEG - 1) ? 1 : 0;
    }
    __syncthreads();
    if (!lastFlag) return;
    __threadfence();               // acquire

    // ---- stage MLP weights (tail block only) ----
    if (tid < 780) {
        int i = tid;
        float v;
        if (i < 192) v = wp_w1[i];
        else if (i < 224) v = wp_b1[i - 192];
        else if (i < 736) v = wp_w2[i - 224];
        else if (i < 752) v = wp_b2[i - 736];
        else if (i < 768) v = wp_w3[i - 752];
        else v = wp_b3[0];
        Wp[i] = v;
    }
    if (tid < 512) {
        int o = tid >> 5, ci = tid & 31;
        Wt2[ci * 16 + o] = wp_w2[tid];
    }
    __syncthreads();

    // ---- wave-parallel resolve: wave w owns j in [colbase + w*32, +32) ----
    int w = tid >> 6;
    int lane = tid & 63;
    int jw = blockIdx.x * (256 * JB) + w * 32;
    int myM = 0;
    if (lane < 32) {
        u64 pkv = atomicAdd(&packed[jw + lane], 0ULL);   // coherent atomic read
        myM = (int)(unsigned)(pkv & 0xFFFFFFFFull);
    }
    for (int it = 0; it < 32; ++it) {
        int j = jw + it;
        int m = __shfl(myM, it);                 // 32-bit shuffle, wave-uniform result
        float qx0 = P[j * 3 + 0], qx1 = P[j * 3 + 1], qx2 = P[j * 3 + 2];
        float cmx = C[m * 3 + 0], cmy = C[m * 3 + 1], cmz = C[m * 3 + 2];

        int c1 = lane & 31;                      // h1 channel (verbatim round-9 chain)
        float acc1 = 0.0f;
        acc1 = __builtin_fmaf(qx0, Wp[c1 * 6 + 0], acc1);
        acc1 = __builtin_fmaf(qx1, Wp[c1 * 6 + 1], acc1);
        acc1 = __builtin_fmaf(qx2, Wp[c1 * 6 + 2], acc1);
        acc1 = __builtin_fmaf(cmx, Wp[c1 * 6 + 3], acc1);
        acc1 = __builtin_fmaf(cmy, Wp[c1 * 6 + 4], acc1);
        acc1 = __builtin_fmaf(cmz, Wp[c1 * 6 + 5], acc1);
        float h1 = fmaxf(acc1 + Wp[192 + c1], 0.0f);

        int c2 = lane & 15;                      // h2 channel
        float acc2 = 0.0f;
#pragma unroll
        for (int ci = 0; ci < 32; ++ci)
            acc2 = __builtin_fmaf(__shfl(h1, ci), Wt2[ci * 16 + c2], acc2);
        float h2 = fmaxf(acc2 + Wp[736 + c2], 0.0f);

        float acc3 = 0.0f;                       // z (identical on all lanes)
#pragma unroll
        for (int ci = 0; ci < 16; ++ci)
            acc3 = __builtin_fmaf(__shfl(h2, ci), Wp[752 + ci], acc3);
        float z = acc3 + Wp[768];
        float ww = 1.0f / (1.0f + expf(-z));
        float omw = 1.0f - ww;

        if (lane < 3) {
            float xe = (lane == 0) ? qx0 : (lane == 1) ? qx1 : qx2;
            float ce = (lane == 0) ? cmx : (lane == 1) ? cmy : cmz;
            float t1 = ww * xe;
            float t2 = omw * ce;
            fused[lane * NPTS + j] = t1 + t2;
        }
        if (lane == 0) {
            mi[j] = m;
            atomicMax(&jmax[m], j);
        }
    }
}

// ---------------------------------------------------------------------------
// fused boundary smoother + scatter epilogue (verbatim round-12 body).
__global__ __launch_bounds__(256) void k_smoother(const float* __restrict__ fused,
        const float* __restrict__ w1g, const float* __restrict__ b1g,
        const float* __restrict__ W2Tg, const float* __restrict__ b2g,
        const float* __restrict__ w3g, const float* __restrict__ b3g,
        float* __restrict__ sm, const int* __restrict__ mi,
        const int* __restrict__ jmax, float* __restrict__ finNext) {
#pragma clang fp contract(off)
    __shared__ float F[3][28];
    __shared__ float H1[32][25];   // 24 used + 1 pad (odd stride: conflict-free)
    __shared__ float H2[32][21];   // 20 used + 1 pad
    __shared__ float W2[5120];
    __shared__ float B2[32];
    int tid = threadIdx.x;
    int BASE = blockIdx.x * SROWS;

    for (int li = tid; li < 84; li += 256) {
        int c = li / 28, i = li % 28;
        int t = BASE - 6 + i;
        F[c][i] = (t >= 0 && t < NPTS) ? fused[c * NPTS + t] : 0.0f;
    }
    for (int li = tid; li < 1280; li += 256)
        ((float4*)W2)[li] = ((const float4*)W2Tg)[li];
    if (tid < 32) B2[tid] = b2g[tid];
    __syncthreads();

    // ---- layer 1: 32 co x 24 positions, 3 positions per thread ----
    {
        int co = tid >> 3, pg = tid & 7;
        float wr[15];
#pragma unroll
        for (int q = 0; q < 15; ++q) wr[q] = w1g[co * 15 + q];
        float bias = b1g[co];
#pragma unroll
        for (int s = 0; s < 3; ++s) {
            int i = pg * 3 + s;
            int t = BASE - 4 + i;
            float acc = 0.0f;
#pragma unroll
            for (int k = 0; k < 5; ++k)
#pragma unroll
                for (int ci = 0; ci < 3; ++ci)
                    acc = __builtin_fmaf(F[ci][i + k], wr[ci * 5 + k], acc);
            H1[co][i] = (t >= 0 && t < NPTS) ? fmaxf(acc + bias, 0.0f) : 0.0f;
        }
    }
    __syncthreads();

    // ---- layer 2: 20 positions x 8 co-quads, 2 positions per thread ----
    {
        int cq = tid & 7, pq = tid >> 3;
        if (pq < 10) {
            int i2 = pq * 2;
            int co0 = cq * 4;
            float acc00 = 0.f, acc01 = 0.f, acc02 = 0.f, acc03 = 0.f;
            float acc10 = 0.f, acc11 = 0.f, acc12 = 0.f, acc13 = 0.f;
            for (int k = 0; k < 5; ++k) {
#pragma unroll
                for (int ci = 0; ci < 32; ++ci) {
                    float in0 = H1[ci][i2 + k];
                    float in1 = H1[ci][i2 + k + 1];
                    const float4 wv = *(const float4*)&W2[(ci * 5 + k) * 32 + co0];
                    acc00 = __builtin_fmaf(in0, wv.x, acc00);
                    acc01 = __builtin_fmaf(in0, wv.y, acc01);
                    acc02 = __builtin_fmaf(in0, wv.z, acc02);
                    acc03 = __builtin_fmaf(in0, wv.w, acc03);
                    acc10 = __builtin_fmaf(in1, wv.x, acc10);
                    acc11 = __builtin_fmaf(in1, wv.y, acc11);
                    acc12 = __builtin_fmaf(in1, wv.z, acc12);
                    acc13 = __builtin_fmaf(in1, wv.w, acc13);
                }
            }
            int t0 = BASE - 2 + i2, t1 = t0 + 1;
            bool ok0 = (t0 >= 0 && t0 < NPTS), ok1 = (t1 >= 0 && t1 < NPTS);
            H2[co0 + 0][i2]     = ok0 ? fmaxf(acc00 + B2[co0 + 0], 0.0f) : 0.0f;
            H2[co0 + 1][i2]     = ok0 ? fmaxf(acc01 + B2[co0 + 1], 0.0f) : 0.0f;
            H2[co0 + 2][i2]     = ok0 ? fmaxf(acc02 + B2[co0 + 2], 0.0f) : 0.0f;
            H2[co0 + 3][i2]     = ok0 ? fmaxf(acc03 + B2[co0 + 3], 0.0f) : 0.0f;
            H2[co0 + 0][i2 + 1] = ok1 ? fmaxf(acc10 + B2[co0 + 0], 0.0f) : 0.0f;
            H2[co0 + 1][i2 + 1] = ok1 ? fmaxf(acc11 + B2[co0 + 1], 0.0f) : 0.0f;
            H2[co0 + 2][i2 + 1] = ok1 ? fmaxf(acc12 + B2[co0 + 2], 0.0f) : 0.0f;
            H2[co0 + 3][i2 + 1] = ok1 ? fmaxf(acc13 + B2[co0 + 3], 0.0f) : 0.0f;
        }
    }
    __syncthreads();

    // ---- layer 3: 3 co x 16 positions + fused scatter ----
    if (tid < 48) {
        int co = tid >> 4, p = tid & 15;
        float wr[160];
        const float4* w3v = (const float4*)(w3g + co * 160);
#pragma unroll
        for (int q = 0; q < 40; ++q) {
            float4 v = w3v[q];
            wr[q * 4 + 0] = v.x; wr[q * 4 + 1] = v.y;
            wr[q * 4 + 2] = v.z; wr[q * 4 + 3] = v.w;
        }
        float acc = 0.0f;
#pragma unroll
        for (int k = 0; k < 5; ++k)
#pragma unroll
            for (int ci = 0; ci < 32; ++ci)
                acc = __builtin_fmaf(H2[ci][p + k], wr[ci * 5 + k], acc);
        float val = acc + b3g[co];
        int jj = BASE + p;
        sm[jj * 3 + co] = val;
        // fused scatter: unique winner j per k (jmax finalized in argmin tail)
        int kk = mi[jj];
        if (jmax[kk] == jj) finNext[kk * 3 + co] = val;
    }
}

// ---------------------------------------------------------------------------
__global__ void k_merge(const float* __restrict__ fin, float* __restrict__ out) {
#pragma clang fp contract(off)
    int pos = blockIdx.x * 256 + threadIdx.x;
    if (pos >= TOTAL) return;
    int imax = pos / STRIDE; if (imax > NCH - 1) imax = NCH - 1;
    int imin = (pos >= NPTS) ? ((pos - NPTS) / STRIDE + 1) : 0;
    float a0 = 0.0f, a1 = 0.0f, a2 = 0.0f, wsum = 0.0f;
    const float kstep = 0.9f / 1227.0f;
    for (int i = imin; i <= imax; ++i) {
        int t = pos - i * STRIDE;
        float cw;
        if (t < FADE)                cw = 0.1f + (float)t * kstep;
        else if (t >= NPTS - FADE)   cw = 1.0f - (float)(t - (NPTS - FADE)) * kstep;
        else                         cw = 1.0f;
        const float* v = fin + (i * NPTS + t) * 3;
        a0 += cw * v[0];
        a1 += cw * v[1];
        a2 += cw * v[2];
        wsum += cw;
    }
    float wm = fmaxf(wsum, 1e-8f);
    out[pos * 3 + 0] = a0 / wm;
    out[pos * 3 + 1] = a1 / wm;
    out[pos * 3 + 2] = a2 / wm;
}

// ---------------------------------------------------------------------------
extern "C" void kernel_launch(void* const* d_in, const int* in_sizes, int n_in,
                              void* d_out, int out_size, void* d_ws, size_t ws_size,
                              hipStream_t stream) {
    const float* chunks = (const float*)d_in[0];
    const float* bs_w1 = (const float*)d_in[1];
    const float* bs_b1 = (const float*)d_in[2];
    const float* bs_w2 = (const float*)d_in[3];
    const float* bs_b2 = (const float*)d_in[4];
    const float* bs_w3 = (const float*)d_in[5];
    const float* bs_b3 = (const float*)d_in[6];
    const float* wp_w1 = (const float*)d_in[7];
    const float* wp_b1 = (const float*)d_in[8];
    const float* wp_w2 = (const float*)d_in[9];
    const float* wp_b2 = (const float*)d_in[10];
    const float* wp_w3 = (const float*)d_in[11];
    const float* wp_b3 = (const float*)d_in[12];

    u64* packed_all = (u64*)d_ws;                                 // 7*8192 u64 (8B-aligned base)
    float* fin      = (float*)(packed_all + (NCH - 1) * NPTS);    // 196608 f32
    float* fused    = fin + NCH * NPTS * 3;                       // 24576 f32
    int*   mi       = (int*)(fused + 3 * NPTS);                   // 8192 i32
    int*   jmax_all = mi + NPTS;                                  // 57344 i32
    float* W2T      = (float*)(jmax_all + (NCH - 1) * NPTS);      // 5120 f32
    int*   tickets  = (int*)(W2T + 5120);                         // 112 i32
    // total ~1.66 MB

    k_setup<<<768, 256, 0, stream>>>(chunks, fin, jmax_all, (unsigned int*)packed_all,
                                     bs_w2, W2T, tickets);

    for (int i = 1; i < NCH; ++i) {
        const float* C = chunks + i * NPTS * 3;
        float* P  = fin + (i - 1) * NPTS * 3;
        float* Pn = fin + i * NPTS * 3;
        u64* packed = packed_all + (i - 1) * NPTS;
        int* jmax = jmax_all + (i - 1) * NPTS;
        int* ticket = tickets + (i - 1) * NCOL;

        k_argmin<<<dim3(NCOL, SEG), 1024, 0, stream>>>(P, C, packed, ticket,
                wp_w1, wp_b1, wp_w2, wp_b2, wp_w3, wp_b3, fused, mi, jmax);
        k_smoother<<<NPTS / SROWS, 256, 0, stream>>>(fused, bs_w1, bs_b1, W2T, bs_b2,
                                                     bs_w3, bs_b3, P, mi, jmax, Pn);
    }

    k_merge<<<200, 256, 0, stream>>>(fin, (float*)d_out);
}

// Round 14
// 299.828 us; speedup vs baseline: 4.9912x; 4.9912x over previous
//
#include <hip/hip_runtime.h>

#define NPTS 8192
#define NCH 8
#define STRIDE 6144
#define TOTAL 51200
#define FADE 1228
#define SEG 32
#define SEGLEN 256   // NPTS / SEG
#define JB 2         // j's per thread in argmin
#define TEAMS 4      // t-range teams per argmin block
#define TLEN 64      // SEGLEN / TEAMS
#define SROWS 16     // smoother rows per block (512 blocks = 2/CU)

// ---------------------------------------------------------------------------
// copy ALL chunks -> fin, init jmax to -1, init packed argmin buffers,
// and pre-transpose bs_w2 into W2T (done once, not per smoother block).
__global__ void k_setup(const float* __restrict__ chunks, float* __restrict__ fin,
                        int* __restrict__ jmax_all, unsigned int* __restrict__ packed32,
                        const float* __restrict__ w2g, float* __restrict__ W2T) {
    int i = blockIdx.x * 256 + threadIdx.x;            // grid covers 196608
    if (i < NCH * NPTS * 3) fin[i] = chunks[i];
    if (i < (NCH - 1) * NPTS) jmax_all[i] = -1;
    if (i < (NCH - 1) * NPTS * 2) packed32[i] = 0xFFFFFFFFu;
    if (i < 5120) {
        int co = i / 160;
        int r = i - co * 160;
        int ci = r / 5;
        int k = r - ci * 5;
        W2T[(ci * 5 + k) * 32 + co] = w2g[i];
    }
}

// ---------------------------------------------------------------------------
// Brute-force argmin over a 256-candidate segment, JB=2 queries per thread.
// d chain bit-identical: g = fma(p2,cz, fma(p1,cy, p0*cx)); sadd = pp + cc;
// d = fma(-2, g, sadd). 1024-thread blocks = 4 t-teams x 256 lanes; teams 1-3
// publish packed (d,k) to LDS, team 0 takes the lexicographic u64 min and
// issues one global atomicMin per j. 512 blocks = 2/CU = full occupancy.
__global__ __launch_bounds__(1024, 8) void k_argmin(const float* __restrict__ P,
                                                    const float* __restrict__ C,
                                                    unsigned long long* __restrict__ packed) {
#pragma clang fp contract(off)
    __shared__ float4 sh[SEGLEN];
    __shared__ unsigned long long pkbuf[TEAMS - 1][256 * JB];
    int tid = threadIdx.x;
    int lt   = tid & 255;          // lane within team (0..255)
    int team = tid >> 8;           // 0..3
    int k0 = blockIdx.y * SEGLEN;
    if (tid < SEGLEN) {
        int k = k0 + tid;
        float x = C[k * 3 + 0], y = C[k * 3 + 1], z = C[k * 3 + 2];
        float cc = (x * x + y * y) + z * z;
        sh[tid] = make_float4(x, y, z, cc);
    }
    __syncthreads();
    int j0 = blockIdx.x * (256 * JB) + lt * JB;
    const float2* Pv = (const float2*)(P + j0 * 3);    // 6 floats, 8B-aligned (j0 even)
    float2 a = Pv[0], b = Pv[1], c2 = Pv[2];
    float p0[JB] = {a.x, b.y};
    float p1[JB] = {a.y, c2.x};
    float p2[JB] = {b.x, c2.y};
    float pp[JB], best[JB];
    int bt[JB];
    int t0 = team * TLEN;
#pragma unroll
    for (int i = 0; i < JB; ++i) {
        pp[i] = (p0[i] * p0[i] + p1[i] * p1[i]) + p2[i] * p2[i];
        best[i] = 3.4e38f;
        bt[i] = t0;
    }
#pragma unroll 4
    for (int tt = 0; tt < TLEN; ++tt) {
        int t = t0 + tt;
        float4 f = sh[t];
#pragma unroll
        for (int i = 0; i < JB; ++i) {
            float g = __builtin_fmaf(p2[i], f.z, __builtin_fmaf(p1[i], f.y, p0[i] * f.x));
            float sadd = pp[i] + f.w;
            float d = __builtin_fmaf(-2.0f, g, sadd);
            if (d < best[i]) { best[i] = d; bt[i] = t; }   // strict <: lowest t wins ties
        }
    }
    unsigned long long pk[JB];
#pragma unroll
    for (int i = 0; i < JB; ++i) {
        unsigned ud = __float_as_uint(best[i]);
        if (ud == 0x80000000u) ud = 0u;                 // canonicalize -0 -> +0 (bitwise)
        ud = (ud & 0x80000000u) ? ~ud : (ud | 0x80000000u);   // order-preserving map
        pk[i] = ((unsigned long long)ud << 32)
              | (unsigned long long)(unsigned)(k0 + bt[i]);
    }
    if (team > 0) {
#pragma unroll
        for (int i = 0; i < JB; ++i) pkbuf[team - 1][lt * JB + i] = pk[i];
    }
    __syncthreads();
    if (team == 0) {
#pragma unroll
        for (int i = 0; i < JB; ++i) {
            unsigned long long v = pk[i];
            unsigned long long v1 = pkbuf[0][lt * JB + i];
            unsigned long long v2 = pkbuf[1][lt * JB + i];
            unsigned long long v3 = pkbuf[2][lt * JB + i];
            if (v1 < v) v = v1;
            if (v2 < v) v = v2;
            if (v3 < v) v = v3;
            atomicMin(&packed[j0 + i], v);
        }
    }
}

// ---------------------------------------------------------------------------
// unpack match index + weight-predictor MLP (weights in LDS) + fused-combine
// + deduped jmax atomicMax. 64 blocks x 128 threads, one query per thread.
__global__ __launch_bounds__(128) void k_resolve(
        const float* __restrict__ P, const float* __restrict__ C,
        const unsigned long long* __restrict__ packed,
        const float* __restrict__ w1g, const float* __restrict__ b1g,
        const float* __restrict__ w2g, const float* __restrict__ b2g,
        const float* __restrict__ w3g, const float* __restrict__ b3g,
        float* __restrict__ fused, int* __restrict__ mi, int* __restrict__ jmax) {
#pragma clang fp contract(off)
    __shared__ float W[780];   // w1[0:192) b1[192:224) w2[224:736) b2[736:752) w3[752:768) b3[768]
    int tid = threadIdx.x;
    for (int i = tid; i < 780; i += 128) {
        float v;
        if (i < 192) v = w1g[i];
        else if (i < 224) v = b1g[i - 192];
        else if (i < 736) v = w2g[i - 224];
        else if (i < 752) v = b2g[i - 736];
        else if (i < 768) v = w3g[i - 752];
        else v = b3g[0];
        W[i] = v;
    }
    __syncthreads();

    int j = blockIdx.x * 128 + tid;
    int m = (int)(unsigned)(packed[j] & 0xFFFFFFFFull);
    mi[j] = m;
    float x6[6];
    x6[0] = P[j * 3 + 0]; x6[1] = P[j * 3 + 1]; x6[2] = P[j * 3 + 2];
    x6[3] = C[m * 3 + 0]; x6[4] = C[m * 3 + 1]; x6[5] = C[m * 3 + 2];

    float h1[32];
#pragma unroll
    for (int o = 0; o < 32; ++o) {
        float acc = 0.0f;
#pragma unroll
        for (int ci = 0; ci < 6; ++ci) acc = __builtin_fmaf(x6[ci], W[o * 6 + ci], acc);
        h1[o] = fmaxf(acc + W[192 + o], 0.0f);
    }
    float h2[16];
#pragma unroll
    for (int o = 0; o < 16; ++o) {
        float acc = 0.0f;
#pragma unroll
        for (int ci = 0; ci < 32; ++ci) acc = __builtin_fmaf(h1[ci], W[224 + o * 32 + ci], acc);
        h2[o] = fmaxf(acc + W[736 + o], 0.0f);
    }
    float acc = 0.0f;
#pragma unroll
    for (int ci = 0; ci < 16; ++ci) acc = __builtin_fmaf(h2[ci], W[752 + ci], acc);
    float z = acc + W[768];
    float w = 1.0f / (1.0f + expf(-z));
    float omw = 1.0f - w;
#pragma unroll
    for (int e = 0; e < 3; ++e) {
        float t1 = w * x6[e];
        float t2 = omw * x6[3 + e];
        fused[e * NPTS + j] = t1 + t2;
    }

    // wave-level dedupe: only the highest-j lane per distinct m issues the atomic
    int lane = tid & 63;
    bool issue = true;
    for (int s = 1; s < 64; ++s) {
        int om = __shfl_down(m, s);
        if (lane + s < 64 && om == m) issue = false;
    }
    if (issue) atomicMax(&jmax[m], j);
}

// ---------------------------------------------------------------------------
// fused boundary smoother + scatter epilogue. 512 blocks x 16 rows
// (2 blocks/CU so one block's compute overlaps the other's staging/barriers);
// W2 read pre-transposed (linear float4, no per-element index math). Every
// (position,channel) accumulator keeps the exact original k-outer/ci-inner
// FMA order -> bit-identical results.
__global__ __launch_bounds__(256) void k_smoother(const float* __restrict__ fused,
        const float* __restrict__ w1g, const float* __restrict__ b1g,
        const float* __restrict__ W2Tg, const float* __restrict__ b2g,
        const float* __restrict__ w3g, const float* __restrict__ b3g,
        float* __restrict__ sm, const int* __restrict__ mi,
        const int* __restrict__ jmax, float* __restrict__ finNext) {
#pragma clang fp contract(off)
    __shared__ float F[3][28];
    __shared__ float H1[32][25];   // 24 used + 1 pad (odd stride: conflict-free)
    __shared__ float H2[32][21];   // 20 used + 1 pad
    __shared__ float W2[5120];
    __shared__ float B2[32];
    int tid = threadIdx.x;
    int BASE = blockIdx.x * SROWS;

    for (int li = tid; li < 84; li += 256) {
        int c = li / 28, i = li % 28;
        int t = BASE - 6 + i;
        F[c][i] = (t >= 0 && t < NPTS) ? fused[c * NPTS + t] : 0.0f;
    }
    for (int li = tid; li < 1280; li += 256)
        ((float4*)W2)[li] = ((const float4*)W2Tg)[li];
    if (tid < 32) B2[tid] = b2g[tid];
    __syncthreads();

    // ---- layer 1: 32 co x 24 positions, 3 positions per thread ----
    {
        int co = tid >> 3, pg = tid & 7;
        float wr[15];
#pragma unroll
        for (int q = 0; q < 15; ++q) wr[q] = w1g[co * 15 + q];
        float bias = b1g[co];
#pragma unroll
        for (int s = 0; s < 3; ++s) {
            int i = pg * 3 + s;
            int t = BASE - 4 + i;
            float acc = 0.0f;
#pragma unroll
            for (int k = 0; k < 5; ++k)
#pragma unroll
                for (int ci = 0; ci < 3; ++ci)
                    acc = __builtin_fmaf(F[ci][i + k], wr[ci * 5 + k], acc);
            H1[co][i] = (t >= 0 && t < NPTS) ? fmaxf(acc + bias, 0.0f) : 0.0f;
        }
    }
    __syncthreads();

    // ---- layer 2: 20 positions x 8 co-quads, 2 positions per thread ----
    {
        int cq = tid & 7, pq = tid >> 3;
        if (pq < 10) {
            int i2 = pq * 2;
            int co0 = cq * 4;
            float acc00 = 0.f, acc01 = 0.f, acc02 = 0.f, acc03 = 0.f;
            float acc10 = 0.f, acc11 = 0.f, acc12 = 0.f, acc13 = 0.f;
            for (int k = 0; k < 5; ++k) {
#pragma unroll
                for (int ci = 0; ci < 32; ++ci) {
                    float in0 = H1[ci][i2 + k];
                    float in1 = H1[ci][i2 + k + 1];
                    const float4 wv = *(const float4*)&W2[(ci * 5 + k) * 32 + co0];
                    acc00 = __builtin_fmaf(in0, wv.x, acc00);
                    acc01 = __builtin_fmaf(in0, wv.y, acc01);
                    acc02 = __builtin_fmaf(in0, wv.z, acc02);
                    acc03 = __builtin_fmaf(in0, wv.w, acc03);
                    acc10 = __builtin_fmaf(in1, wv.x, acc10);
                    acc11 = __builtin_fmaf(in1, wv.y, acc11);
                    acc12 = __builtin_fmaf(in1, wv.z, acc12);
                    acc13 = __builtin_fmaf(in1, wv.w, acc13);
                }
            }
            int t0 = BASE - 2 + i2, t1 = t0 + 1;
            bool ok0 = (t0 >= 0 && t0 < NPTS), ok1 = (t1 >= 0 && t1 < NPTS);
            H2[co0 + 0][i2]     = ok0 ? fmaxf(acc00 + B2[co0 + 0], 0.0f) : 0.0f;
            H2[co0 + 1][i2]     = ok0 ? fmaxf(acc01 + B2[co0 + 1], 0.0f) : 0.0f;
            H2[co0 + 2][i2]     = ok0 ? fmaxf(acc02 + B2[co0 + 2], 0.0f) : 0.0f;
            H2[co0 + 3][i2]     = ok0 ? fmaxf(acc03 + B2[co0 + 3], 0.0f) : 0.0f;
            H2[co0 + 0][i2 + 1] = ok1 ? fmaxf(acc10 + B2[co0 + 0], 0.0f) : 0.0f;
            H2[co0 + 1][i2 + 1] = ok1 ? fmaxf(acc11 + B2[co0 + 1], 0.0f) : 0.0f;
            H2[co0 + 2][i2 + 1] = ok1 ? fmaxf(acc12 + B2[co0 + 2], 0.0f) : 0.0f;
            H2[co0 + 3][i2 + 1] = ok1 ? fmaxf(acc13 + B2[co0 + 3], 0.0f) : 0.0f;
        }
    }
    __syncthreads();

    // ---- layer 3: 3 co x 16 positions + fused scatter ----
    if (tid < 48) {
        int co = tid >> 4, p = tid & 15;
        float wr[160];
        const float4* w3v = (const float4*)(w3g + co * 160);
#pragma unroll
        for (int q = 0; q < 40; ++q) {
            float4 v = w3v[q];
            wr[q * 4 + 0] = v.x; wr[q * 4 + 1] = v.y;
            wr[q * 4 + 2] = v.z; wr[q * 4 + 3] = v.w;
        }
        float acc = 0.0f;
#pragma unroll
        for (int k = 0; k < 5; ++k)
#pragma unroll
            for (int ci = 0; ci < 32; ++ci)
                acc = __builtin_fmaf(H2[ci][p + k], wr[ci * 5 + k], acc);
        float val = acc + b3g[co];
        int jj = BASE + p;
        sm[jj * 3 + co] = val;
        // fused scatter: unique winner j per k (jmax finalized in k_resolve)
        int kk = mi[jj];
        if (jmax[kk] == jj) finNext[kk * 3 + co] = val;
    }
}

// ---------------------------------------------------------------------------
__global__ void k_merge(const float* __restrict__ fin, float* __restrict__ out) {
#pragma clang fp contract(off)
    int pos = blockIdx.x * 256 + threadIdx.x;
    if (pos >= TOTAL) return;
    int imax = pos / STRIDE; if (imax > NCH - 1) imax = NCH - 1;
    int imin = (pos >= NPTS) ? ((pos - NPTS) / STRIDE + 1) : 0;
    float a0 = 0.0f, a1 = 0.0f, a2 = 0.0f, wsum = 0.0f;
    const float kstep = 0.9f / 1227.0f;
    for (int i = imin; i <= imax; ++i) {
        int t = pos - i * STRIDE;
        float cw;
        if (t < FADE)                cw = 0.1f + (float)t * kstep;
        else if (t >= NPTS - FADE)   cw = 1.0f - (float)(t - (NPTS - FADE)) * kstep;
        else                         cw = 1.0f;
        const float* v = fin + (i * NPTS + t) * 3;
        a0 += cw * v[0];
        a1 += cw * v[1];
        a2 += cw * v[2];
        wsum += cw;
    }
    float wm = fmaxf(wsum, 1e-8f);
    out[pos * 3 + 0] = a0 / wm;
    out[pos * 3 + 1] = a1 / wm;
    out[pos * 3 + 2] = a2 / wm;
}

// ---------------------------------------------------------------------------
extern "C" void kernel_launch(void* const* d_in, const int* in_sizes, int n_in,
                              void* d_out, int out_size, void* d_ws, size_t ws_size,
                              hipStream_t stream) {
    const float* chunks = (const float*)d_in[0];
    const float* bs_w1 = (const float*)d_in[1];
    const float* bs_b1 = (const float*)d_in[2];
    const float* bs_w2 = (const float*)d_in[3];
    const float* bs_b2 = (const float*)d_in[4];
    const float* bs_w3 = (const float*)d_in[5];
    const float* bs_b3 = (const float*)d_in[6];
    const float* wp_w1 = (const float*)d_in[7];
    const float* wp_b1 = (const float*)d_in[8];
    const float* wp_w2 = (const float*)d_in[9];
    const float* wp_b2 = (const float*)d_in[10];
    const float* wp_w3 = (const float*)d_in[11];
    const float* wp_b3 = (const float*)d_in[12];

    unsigned long long* packed_all = (unsigned long long*)d_ws;   // 7*8192 u64 (8B-aligned base)
    float* fin      = (float*)(packed_all + (NCH - 1) * NPTS);    // 196608 f32
    float* fused    = fin + NCH * NPTS * 3;                       // 24576 f32
    int*   mi       = (int*)(fused + 3 * NPTS);                   // 8192 i32
    int*   jmax_all = mi + NPTS;                                  // 57344 i32
    float* W2T      = (float*)(jmax_all + (NCH - 1) * NPTS);      // 5120 f32
    // total ~1.66 MB

    k_setup<<<768, 256, 0, stream>>>(chunks, fin, jmax_all, (unsigned int*)packed_all,
                                     bs_w2, W2T);

    for (int i = 1; i < NCH; ++i) {
        const float* C = chunks + i * NPTS * 3;
        float* P  = fin + (i - 1) * NPTS * 3;
        float* Pn = fin + i * NPTS * 3;
        unsigned long long* packed = packed_all + (i - 1) * NPTS;
        int* jmax = jmax_all + (i - 1) * NPTS;

        k_argmin<<<dim3(NPTS / (256 * JB), SEG), 1024, 0, stream>>>(P, C, packed);
        k_resolve<<<64, 128, 0, stream>>>(P, C, packed, wp_w1, wp_b1, wp_w2, wp_b2,
                                          wp_w3, wp_b3, fused, mi, jmax);
        k_smoother<<<NPTS / SROWS, 256, 0, stream>>>(fused, bs_w1, bs_b1, W2T, bs_b2,
                                                     bs_w3, bs_b3, P, mi, jmax, Pn);
    }

    k_merge<<<200, 256, 0, stream>>>(fin, (float*)d_out);
}